// Round 4
// baseline (682.832 us; speedup 1.0000x reference)
//
#include <hip/hip_runtime.h>
#include <math.h>

#define LN2F 0.69314718055994531f

typedef _Float16 v8hf __attribute__((ext_vector_type(8)));
typedef float    v4f  __attribute__((ext_vector_type(4)));

// fast shifted-softplus via v_exp_f32/v_log_f32 (~10 VALU instr vs ~50 libm).
__device__ __forceinline__ float ssp_fast(float x) {
    float e = __expf(-fabsf(x));
    return fmaxf(x, 0.f) + __logf(1.f + e) - LN2F;
}

// ---------------------------------------------------------------------------
// Prep: weights -> f16, MFMA-B-fragment order.
// ---------------------------------------------------------------------------
__global__ __launch_bounds__(256)
void prep_kernel(const float* __restrict__ w1, const float* __restrict__ w2,
                 const float* __restrict__ l1w, const float* __restrict__ l2w,
                 const float* __restrict__ lw,
                 _Float16* __restrict__ w1f, _Float16* __restrict__ w2f,
                 _Float16* __restrict__ l1f, _Float16* __restrict__ l2f,
                 _Float16* __restrict__ lwf)
{
    int idx = blockIdx.x * 256 + threadIdx.x;
    if (idx < 8192) {  // w1f
        int i = idx & 7, lane = (idx >> 3) & 63, ks = (idx >> 9) & 1, nt = idx >> 10;
        int r = nt * 16 + (lane & 15);
        int k = ks * 32 + (lane >> 4) * 8 + i;
        w1f[idx] = (k < 50) ? (_Float16)w1[r * 50 + k] : (_Float16)0.f;
        return;
    }
    int o = idx - 8192;
    if (o >= 4 * 16384) return;
    int which = o >> 14;
    int p = o & 16383;
    int i = p & 7, lane = (p >> 3) & 63, ks = (p >> 9) & 3, nt = p >> 11;
    int r = nt * 16 + (lane & 15);
    int k = ks * 32 + (lane >> 4) * 8 + i;
    const float* src = (which == 0) ? w2 : (which == 1) ? l1w : (which == 2) ? l2w : lw;
    _Float16* dst   = (which == 0) ? w2f : (which == 1) ? l1f : (which == 2) ? l2f : lwf;
    dst[p] = (_Float16)src[r * 128 + k];
}

// ---------------------------------------------------------------------------
// h = X @ W^T (no bias/act). Column-split across blockIdx.y for 2x blocks.
// ---------------------------------------------------------------------------
__global__ __launch_bounds__(256)
void h_gemm_kernel(const float* __restrict__ X, const _Float16* __restrict__ Wf,
                   float* __restrict__ Y, int M)
{
    const int tid = threadIdx.x, lane = tid & 63, wv = tid >> 6;
    const int l15 = lane & 15, quad = lane >> 4;
    const int mb = blockIdx.x * 64 + wv * 16;
    const int nt0 = blockIdx.y * 4;

    const int mA = (mb + l15 < M) ? (mb + l15) : (M - 1);
    v8hf a[4];
    #pragma unroll
    for (int ks = 0; ks < 4; ++ks) {
        const float4* xp = (const float4*)&X[(size_t)mA * 128 + ks * 32 + quad * 8];
        float4 x0 = xp[0], x1 = xp[1];
        v8hf t = {(_Float16)x0.x, (_Float16)x0.y, (_Float16)x0.z, (_Float16)x0.w,
                  (_Float16)x1.x, (_Float16)x1.y, (_Float16)x1.z, (_Float16)x1.w};
        a[ks] = t;
    }
    #pragma unroll
    for (int nt = nt0; nt < nt0 + 4; ++nt) {
        v4f acc = {0.f, 0.f, 0.f, 0.f};
        #pragma unroll
        for (int ks = 0; ks < 4; ++ks) {
            const v8hf b = *(const v8hf*)&Wf[((nt * 4 + ks) * 64 + lane) * 8];
            acc = __builtin_amdgcn_mfma_f32_16x16x32_f16(a[ks], b, acc, 0, 0, 0);
        }
        const int col = nt * 16 + l15;
        #pragma unroll
        for (int r = 0; r < 4; ++r) {
            int row = mb + quad * 4 + r;
            if (row < M) Y[(size_t)row * 128 + col] = acc[r];
        }
    }
}

// ---------------------------------------------------------------------------
// Fused tail: out = ssp(agg @ l2^T + l2b) @ lw^T + lb.
// Stage-2 column-split across blockIdx.y (stage-1 recomputed, MFMA is cheap).
// ---------------------------------------------------------------------------
__global__ __launch_bounds__(256)
void fused_out_kernel(const float* __restrict__ agg, const _Float16* __restrict__ l2f,
                      const float* __restrict__ l2b, const _Float16* __restrict__ lwf,
                      const float* __restrict__ lb, float* __restrict__ out, int M)
{
    __shared__ __align__(16) _Float16 Sh[64 * 138];
    const int tid = threadIdx.x, lane = tid & 63, wv = tid >> 6;
    const int l15 = lane & 15, quad = lane >> 4;
    const int m0 = wv * 16;
    const int gbase = blockIdx.x * 64;
    const int nt0 = blockIdx.y * 4;

    const int mA = (gbase + m0 + l15 < M) ? (gbase + m0 + l15) : (M - 1);
    v8hf a[4];
    #pragma unroll
    for (int ks = 0; ks < 4; ++ks) {
        const float4* xp = (const float4*)&agg[(size_t)mA * 128 + ks * 32 + quad * 8];
        float4 x0 = xp[0], x1 = xp[1];
        v8hf t = {(_Float16)x0.x, (_Float16)x0.y, (_Float16)x0.z, (_Float16)x0.w,
                  (_Float16)x1.x, (_Float16)x1.y, (_Float16)x1.z, (_Float16)x1.w};
        a[ks] = t;
    }
    #pragma unroll
    for (int nt = 0; nt < 8; ++nt) {
        v4f acc = {0.f, 0.f, 0.f, 0.f};
        #pragma unroll
        for (int ks = 0; ks < 4; ++ks) {
            const v8hf b = *(const v8hf*)&l2f[((nt * 4 + ks) * 64 + lane) * 8];
            acc = __builtin_amdgcn_mfma_f32_16x16x32_f16(a[ks], b, acc, 0, 0, 0);
        }
        const float bj = l2b[nt * 16 + l15];
        #pragma unroll
        for (int r = 0; r < 4; ++r)
            Sh[(m0 + quad * 4 + r) * 138 + nt * 16 + l15] =
                (_Float16)ssp_fast(acc[r] + bj);
    }
    v8hf ua[4];
    #pragma unroll
    for (int ks = 0; ks < 4; ++ks)
        ua[ks] = *(const v8hf*)&Sh[(m0 + l15) * 138 + ks * 32 + quad * 8];

    #pragma unroll
    for (int nt = nt0; nt < nt0 + 4; ++nt) {
        v4f acc = {0.f, 0.f, 0.f, 0.f};
        #pragma unroll
        for (int ks = 0; ks < 4; ++ks) {
            const v8hf b = *(const v8hf*)&lwf[((nt * 4 + ks) * 64 + lane) * 8];
            acc = __builtin_amdgcn_mfma_f32_16x16x32_f16(ua[ks], b, acc, 0, 0, 0);
        }
        const int col = nt * 16 + l15;
        const float bj = lb[col];
        #pragma unroll
        for (int r = 0; r < 4; ++r) {
            int row = gbase + m0 + quad * 4 + r;
            if (row < M) out[(size_t)row * 128 + col] = acc[r] + bj;
        }
    }
}

// ---------------------------------------------------------------------------
// src-CSR build: histogram -> exclusive scan -> rank-scatter with permuted
// metadata emission.
// ---------------------------------------------------------------------------
__global__ __launch_bounds__(256)
void hist_kernel(const int* __restrict__ key, int* __restrict__ counts, int E)
{
    int i = blockIdx.x * 256 + threadIdx.x;
    const int stride = gridDim.x * 256;
    for (; i < E; i += stride) atomicAdd(&counts[key[i]], 1);
}

__global__ __launch_bounds__(256)
void scan1_kernel(int* __restrict__ data, int* __restrict__ bsum, int N)
{
    __shared__ int wsum[4];
    const int t = threadIdx.x, lane = t & 63, wv = t >> 6;
    const int base = blockIdx.x * 1024 + t * 4;
    int v0 = 0, v1 = 0, v2 = 0, v3 = 0;
    if (base + 0 < N) v0 = data[base + 0];
    if (base + 1 < N) v1 = data[base + 1];
    if (base + 2 < N) v2 = data[base + 2];
    if (base + 3 < N) v3 = data[base + 3];
    const int s = v0 + v1 + v2 + v3;
    int sc = s;
    #pragma unroll
    for (int d = 1; d < 64; d <<= 1) {
        int o = __shfl_up(sc, d);
        if (lane >= d) sc += o;
    }
    if (lane == 63) wsum[wv] = sc;
    __syncthreads();
    int wo = 0;
    for (int j = 0; j < wv; ++j) wo += wsum[j];
    int run = wo + (sc - s);
    if (base + 0 < N) data[base + 0] = run; run += v0;
    if (base + 1 < N) data[base + 1] = run; run += v1;
    if (base + 2 < N) data[base + 2] = run; run += v2;
    if (base + 3 < N) data[base + 3] = run; run += v3;
    if (t == 255) bsum[blockIdx.x] = wo + sc;
}

__global__ __launch_bounds__(256)
void scan2_kernel(int* __restrict__ offs, const int* __restrict__ bsum,
                  int* __restrict__ cur, int N, int E)
{
    int add = 0;
    for (int j = 0; j < (int)blockIdx.x; ++j) add += bsum[j];
    const int base = blockIdx.x * 1024 + threadIdx.x * 4;
    #pragma unroll
    for (int r = 0; r < 4; ++r) {
        int i = base + r;
        if (i < N) { int o = offs[i] + add; offs[i] = o; cur[i] = o; }
    }
    if (blockIdx.x == 0 && threadIdx.x == 0) offs[N] = E;
}

// rank[e] = slot; emit permuted src/dst/cosine-envelope arrays.
__global__ __launch_bounds__(256)
void rank_perm_kernel(const int* __restrict__ src, const int* __restrict__ dst,
                      const float* __restrict__ ew, int* __restrict__ cur,
                      int* __restrict__ rank, int* __restrict__ srcP,
                      int* __restrict__ dstP, float* __restrict__ cCP, int E)
{
    int i = blockIdx.x * 256 + threadIdx.x;
    const int stride = gridDim.x * 256;
    for (; i < E; i += stride) {
        const int s = src[i];
        const int p = atomicAdd(&cur[s], 1);
        rank[i] = p;
        srcP[p] = s;
        dstP[p] = dst[i];
        cCP[p] = 0.5f * (__cosf(ew[i] * 0.31415926535897932f) + 1.f);
    }
}

// attr (E x 50 f32) -> attrP (E x 64 f16, zero-padded) at slot rank[e].
// 8 threads per edge; reads coalesced, 16B stores (random 128B rows, f&f).
__global__ __launch_bounds__(256)
void attr_perm_kernel(const float* __restrict__ attr, const int* __restrict__ rank,
                      _Float16* __restrict__ attrP, int E)
{
    int idx = blockIdx.x * 256 + threadIdx.x;
    const int stride = gridDim.x * 256;
    const int total = E * 8;
    for (; idx < total; idx += stride) {
        const int e = idx >> 3, sub = idx & 7;
        const int p = rank[e];
        const float* rp = attr + (size_t)e * 50 + sub * 8;
        v8hf t;
        #pragma unroll
        for (int j = 0; j < 8; ++j) {
            const int c = sub * 8 + j;
            t[j] = (c < 50) ? (_Float16)rp[j] : (_Float16)0.f;
        }
        *(v8hf*)&attrP[(size_t)p * 64 + sub * 8] = t;
    }
}

// ---------------------------------------------------------------------------
// Edge kernel v4: processes SRC-SORTED slots linearly.
//   - attrP f16 64-padded rows: two fully-dense v8hf A-frag loads
//     (16 lines/instr vs ~30 for the 200B-pitch f32 reads; FETCH 274->~95MB).
//   - metadata via float4/int4 (slots consecutive per quad).
//   - h-prefetch: consecutive slots share src (avg degree 16) -> the 32 hv
//     loads hit the same rows block-wide -> L1/L2 broadcast instead of 327MB
//     of random LLC segments (the r1-r3 invariant ~257us floor).
//   - barrier-free (Uh wave-private), (256,7), atomic epilogue unchanged.
// ---------------------------------------------------------------------------
__global__ __launch_bounds__(256, 7)
void edge_kernel(const _Float16* __restrict__ attrP, // E x 64, slot order
                 const float* __restrict__ cCP,      // E
                 const int* __restrict__ srcP,
                 const int* __restrict__ dstP,
                 const _Float16* __restrict__ w1f,
                 const _Float16* __restrict__ w2f,
                 const float* __restrict__ b1,
                 const float* __restrict__ b2,
                 const float* __restrict__ h,        // N x 128
                 float* __restrict__ agg,            // N x 128 (zeroed)
                 int E)
{
    __shared__ __align__(16) _Float16 Uh[64 * 138];

    const int tid = threadIdx.x;
    const int e_base = blockIdx.x * 64;
    const int lane = tid & 63, wv = tid >> 6;
    const int m0 = wv * 16, l15 = lane & 15, quad = lane >> 4;

    // ---- per-lane metadata, vectorized (4 consecutive slots per quad) ----
    const int s0 = e_base + m0 + quad * 4;
    float cC[4]; const float* hrow[4]; float* arow[4]; bool val[4];
    if (s0 + 3 < E) {
        const float4 c4 = *(const float4*)&cCP[s0];
        const int4  sv = *(const int4*)&srcP[s0];
        const int4  dv = *(const int4*)&dstP[s0];
        cC[0] = c4.x; cC[1] = c4.y; cC[2] = c4.z; cC[3] = c4.w;
        hrow[0] = h + (size_t)sv.x * 128; hrow[1] = h + (size_t)sv.y * 128;
        hrow[2] = h + (size_t)sv.z * 128; hrow[3] = h + (size_t)sv.w * 128;
        arow[0] = agg + (size_t)dv.x * 128; arow[1] = agg + (size_t)dv.y * 128;
        arow[2] = agg + (size_t)dv.z * 128; arow[3] = agg + (size_t)dv.w * 128;
        val[0] = val[1] = val[2] = val[3] = true;
    } else {
        #pragma unroll
        for (int r = 0; r < 4; ++r) {
            const int sg = s0 + r;
            val[r] = sg < E;
            const int s = val[r] ? sg : (E - 1);
            cC[r] = cCP[s];
            hrow[r] = h + (size_t)srcP[s] * 128;
            arow[r] = agg + (size_t)dstP[s] * 128;
        }
    }

    // ---- direct A-fragment loads from padded f16 rows (dense) ----
    int sA = e_base + m0 + l15;
    if (sA >= E) sA = E - 1;
    const v8hf a0 = *(const v8hf*)&attrP[(size_t)sA * 64 + quad * 8];
    const v8hf a1 = *(const v8hf*)&attrP[(size_t)sA * 64 + 32 + quad * 8];

    // ---- h-gather prefetch (rows shared block-wide thanks to src sort) ----
    float hv[8][4];
    #pragma unroll
    for (int nt = 0; nt < 8; ++nt)
        #pragma unroll
        for (int r = 0; r < 4; ++r)
            hv[nt][r] = hrow[r][nt * 16 + l15];

    // ---- stage 1: u = ssp(attr @ W1^T + b1) -> Uh (wave-private rows) ----
    #pragma unroll
    for (int nt = 0; nt < 8; ++nt) {
        v4f acc = {0.f, 0.f, 0.f, 0.f};
        const v8hf bA = *(const v8hf*)&w1f[((nt * 2 + 0) * 64 + lane) * 8];
        const v8hf bB = *(const v8hf*)&w1f[((nt * 2 + 1) * 64 + lane) * 8];
        acc = __builtin_amdgcn_mfma_f32_16x16x32_f16(a0, bA, acc, 0, 0, 0);
        acc = __builtin_amdgcn_mfma_f32_16x16x32_f16(a1, bB, acc, 0, 0, 0);
        const float bj = b1[nt * 16 + l15];
        #pragma unroll
        for (int r = 0; r < 4; ++r)
            Uh[(m0 + quad * 4 + r) * 138 + nt * 16 + l15] =
                (_Float16)ssp_fast(acc[r] + bj);
    }

    // ---- stage 2 + D-layout epilogue (wave-private LDS rows, no barrier) ----
    v8hf ua[4];
    #pragma unroll
    for (int ks = 0; ks < 4; ++ks)
        ua[ks] = *(const v8hf*)&Uh[(m0 + l15) * 138 + ks * 32 + quad * 8];

    #pragma unroll
    for (int nt = 0; nt < 8; ++nt) {
        v4f acc = {0.f, 0.f, 0.f, 0.f};
        #pragma unroll
        for (int ks = 0; ks < 4; ++ks) {
            const v8hf b = *(const v8hf*)&w2f[((nt * 4 + ks) * 64 + lane) * 8];
            acc = __builtin_amdgcn_mfma_f32_16x16x32_f16(ua[ks], b, acc, 0, 0, 0);
        }
        const int col = nt * 16 + l15;
        const float bj = b2[col];
        #pragma unroll
        for (int r = 0; r < 4; ++r) {
            if (val[r]) {
                float wf = (acc[r] + bj) * cC[r];
                atomicAdd(&arow[r][col], wf * hv[nt][r]);
            }
        }
    }
}

extern "C" void kernel_launch(void* const* d_in, const int* in_sizes, int n_in,
                              void* d_out, int out_size, void* d_ws, size_t ws_size,
                              hipStream_t stream)
{
    const float* x   = (const float*)d_in[0];
    const int*   ei  = (const int*)  d_in[1];
    const float* ew  = (const float*)d_in[2];
    const float* ea  = (const float*)d_in[3];
    const float* w1  = (const float*)d_in[4];
    const float* b1  = (const float*)d_in[5];
    const float* w2  = (const float*)d_in[6];
    const float* b2  = (const float*)d_in[7];
    const float* l1w = (const float*)d_in[8];
    const float* l2w = (const float*)d_in[9];
    const float* l2b = (const float*)d_in[10];
    const float* lw  = (const float*)d_in[11];
    const float* lb  = (const float*)d_in[12];

    const int N = in_sizes[0] / 128;   // 40000
    const int E = in_sizes[2];         // 640000
    const int NB = (N + 1023) / 1024;

    char* base = (char*)d_ws;
    size_t off = 0;
    auto take = [&](size_t bytes) -> char* {
        char* r = base + off;
        off = (off + bytes + 255) & ~(size_t)255;
        return r;
    };
    float*    hbuf  = (float*)   take((size_t)N * 128 * 4);
    float*    agg   = (float*)   take((size_t)N * 128 * 4);
    _Float16* w1f   = (_Float16*)take(8192 * 2);
    _Float16* w2f   = (_Float16*)take(16384 * 2);
    _Float16* l1f   = (_Float16*)take(16384 * 2);
    _Float16* l2f   = (_Float16*)take(16384 * 2);
    _Float16* lwf   = (_Float16*)take(16384 * 2);
    int*      offs  = (int*)     take((size_t)(N + 1) * 4);
    int*      cur   = (int*)     take((size_t)N * 4);
    int*      bsum  = (int*)     take((size_t)NB * 4);
    int*      rank  = (int*)     take((size_t)E * 4);
    int*      srcP  = (int*)     take((size_t)E * 4);
    int*      dstP  = (int*)     take((size_t)E * 4);
    float*    cCP   = (float*)   take((size_t)E * 4);
    _Float16* attrP = (_Float16*)take((size_t)E * 64 * 2);

    const int nb = (N + 63) / 64;
    const int eb = (E + 63) / 64;
    const int tb = (E + 255) / 256;

    prep_kernel<<<288, 256, 0, stream>>>(w1, w2, l1w, l2w, lw,
                                         w1f, w2f, l1f, l2f, lwf);
    hipMemsetAsync(agg, 0, (size_t)N * 128 * sizeof(float), stream);
    hipMemsetAsync(offs, 0, (size_t)(N + 1) * sizeof(int), stream);
    h_gemm_kernel<<<dim3(nb, 2), 256, 0, stream>>>(x, l1f, hbuf, N);

    // src-CSR + permuted edge data
    hist_kernel<<<tb, 256, 0, stream>>>(ei, offs, E);
    scan1_kernel<<<NB, 256, 0, stream>>>(offs, bsum, N);
    scan2_kernel<<<NB, 256, 0, stream>>>(offs, bsum, cur, N, E);
    rank_perm_kernel<<<tb, 256, 0, stream>>>(ei, ei + E, ew, cur,
                                             rank, srcP, dstP, cCP, E);
    attr_perm_kernel<<<(E * 8 + 255) / 256, 256, 0, stream>>>(ea, rank, attrP, E);

    edge_kernel<<<eb, 256, 0, stream>>>(attrP, cCP, srcP, dstP, w1f, w2f,
                                        b1, b2, hbuf, agg, E);
    fused_out_kernel<<<dim3(nb, 2), 256, 0, stream>>>(agg, l2f, l2b, lwf, lb,
                                                      (float*)d_out, N);
}

// Round 5
// 575.204 us; speedup vs baseline: 1.1871x; 1.1871x over previous
//
#include <hip/hip_runtime.h>
#include <math.h>

#define LN2F 0.69314718055994531f

typedef _Float16 v8hf __attribute__((ext_vector_type(8)));
typedef float    v4f  __attribute__((ext_vector_type(4)));

// fast shifted-softplus via v_exp_f32/v_log_f32 (~10 VALU instr vs ~50 libm).
__device__ __forceinline__ float ssp_fast(float x) {
    float e = __expf(-fabsf(x));
    return fmaxf(x, 0.f) + __logf(1.f + e) - LN2F;
}

// ---------------------------------------------------------------------------
// Prep: weights -> f16, MFMA-B-fragment order.
// ---------------------------------------------------------------------------
__global__ __launch_bounds__(256)
void prep_kernel(const float* __restrict__ w1, const float* __restrict__ w2,
                 const float* __restrict__ l1w, const float* __restrict__ l2w,
                 const float* __restrict__ lw,
                 _Float16* __restrict__ w1f, _Float16* __restrict__ w2f,
                 _Float16* __restrict__ l1f, _Float16* __restrict__ l2f,
                 _Float16* __restrict__ lwf)
{
    int idx = blockIdx.x * 256 + threadIdx.x;
    if (idx < 8192) {  // w1f
        int i = idx & 7, lane = (idx >> 3) & 63, ks = (idx >> 9) & 1, nt = idx >> 10;
        int r = nt * 16 + (lane & 15);
        int k = ks * 32 + (lane >> 4) * 8 + i;
        w1f[idx] = (k < 50) ? (_Float16)w1[r * 50 + k] : (_Float16)0.f;
        return;
    }
    int o = idx - 8192;
    if (o >= 4 * 16384) return;
    int which = o >> 14;
    int p = o & 16383;
    int i = p & 7, lane = (p >> 3) & 63, ks = (p >> 9) & 3, nt = p >> 11;
    int r = nt * 16 + (lane & 15);
    int k = ks * 32 + (lane >> 4) * 8 + i;
    const float* src = (which == 0) ? w2 : (which == 1) ? l1w : (which == 2) ? l2w : lw;
    _Float16* dst   = (which == 0) ? w2f : (which == 1) ? l1f : (which == 2) ? l2f : lwf;
    dst[p] = (_Float16)src[r * 128 + k];
}

// ---------------------------------------------------------------------------
// h = X @ W^T (no bias/act). Column-split across blockIdx.y for 2x blocks.
// ---------------------------------------------------------------------------
__global__ __launch_bounds__(256)
void h_gemm_kernel(const float* __restrict__ X, const _Float16* __restrict__ Wf,
                   float* __restrict__ Y, int M)
{
    const int tid = threadIdx.x, lane = tid & 63, wv = tid >> 6;
    const int l15 = lane & 15, quad = lane >> 4;
    const int mb = blockIdx.x * 64 + wv * 16;
    const int nt0 = blockIdx.y * 4;

    const int mA = (mb + l15 < M) ? (mb + l15) : (M - 1);
    v8hf a[4];
    #pragma unroll
    for (int ks = 0; ks < 4; ++ks) {
        const float4* xp = (const float4*)&X[(size_t)mA * 128 + ks * 32 + quad * 8];
        float4 x0 = xp[0], x1 = xp[1];
        v8hf t = {(_Float16)x0.x, (_Float16)x0.y, (_Float16)x0.z, (_Float16)x0.w,
                  (_Float16)x1.x, (_Float16)x1.y, (_Float16)x1.z, (_Float16)x1.w};
        a[ks] = t;
    }
    #pragma unroll
    for (int nt = nt0; nt < nt0 + 4; ++nt) {
        v4f acc = {0.f, 0.f, 0.f, 0.f};
        #pragma unroll
        for (int ks = 0; ks < 4; ++ks) {
            const v8hf b = *(const v8hf*)&Wf[((nt * 4 + ks) * 64 + lane) * 8];
            acc = __builtin_amdgcn_mfma_f32_16x16x32_f16(a[ks], b, acc, 0, 0, 0);
        }
        const int col = nt * 16 + l15;
        #pragma unroll
        for (int r = 0; r < 4; ++r) {
            int row = mb + quad * 4 + r;
            if (row < M) Y[(size_t)row * 128 + col] = acc[r];
        }
    }
}

// ---------------------------------------------------------------------------
// Fused tail: out = ssp(agg @ l2^T + l2b) @ lw^T + lb.
// Stage-2 column-split across blockIdx.y (stage-1 recomputed, MFMA is cheap).
// ---------------------------------------------------------------------------
__global__ __launch_bounds__(256)
void fused_out_kernel(const float* __restrict__ agg, const _Float16* __restrict__ l2f,
                      const float* __restrict__ l2b, const _Float16* __restrict__ lwf,
                      const float* __restrict__ lb, float* __restrict__ out, int M)
{
    __shared__ __align__(16) _Float16 Sh[64 * 138];
    const int tid = threadIdx.x, lane = tid & 63, wv = tid >> 6;
    const int l15 = lane & 15, quad = lane >> 4;
    const int m0 = wv * 16;
    const int gbase = blockIdx.x * 64;
    const int nt0 = blockIdx.y * 4;

    const int mA = (gbase + m0 + l15 < M) ? (gbase + m0 + l15) : (M - 1);
    v8hf a[4];
    #pragma unroll
    for (int ks = 0; ks < 4; ++ks) {
        const float4* xp = (const float4*)&agg[(size_t)mA * 128 + ks * 32 + quad * 8];
        float4 x0 = xp[0], x1 = xp[1];
        v8hf t = {(_Float16)x0.x, (_Float16)x0.y, (_Float16)x0.z, (_Float16)x0.w,
                  (_Float16)x1.x, (_Float16)x1.y, (_Float16)x1.z, (_Float16)x1.w};
        a[ks] = t;
    }
    #pragma unroll
    for (int nt = 0; nt < 8; ++nt) {
        v4f acc = {0.f, 0.f, 0.f, 0.f};
        #pragma unroll
        for (int ks = 0; ks < 4; ++ks) {
            const v8hf b = *(const v8hf*)&l2f[((nt * 4 + ks) * 64 + lane) * 8];
            acc = __builtin_amdgcn_mfma_f32_16x16x32_f16(a[ks], b, acc, 0, 0, 0);
        }
        const float bj = l2b[nt * 16 + l15];
        #pragma unroll
        for (int r = 0; r < 4; ++r)
            Sh[(m0 + quad * 4 + r) * 138 + nt * 16 + l15] =
                (_Float16)ssp_fast(acc[r] + bj);
    }
    v8hf ua[4];
    #pragma unroll
    for (int ks = 0; ks < 4; ++ks)
        ua[ks] = *(const v8hf*)&Sh[(m0 + l15) * 138 + ks * 32 + quad * 8];

    #pragma unroll
    for (int nt = nt0; nt < nt0 + 4; ++nt) {
        v4f acc = {0.f, 0.f, 0.f, 0.f};
        #pragma unroll
        for (int ks = 0; ks < 4; ++ks) {
            const v8hf b = *(const v8hf*)&lwf[((nt * 4 + ks) * 64 + lane) * 8];
            acc = __builtin_amdgcn_mfma_f32_16x16x32_f16(ua[ks], b, acc, 0, 0, 0);
        }
        const int col = nt * 16 + l15;
        const float bj = lb[col];
        #pragma unroll
        for (int r = 0; r < 4; ++r) {
            int row = gbase + m0 + quad * 4 + r;
            if (row < M) out[(size_t)row * 128 + col] = acc[r] + bj;
        }
    }
}

// ---------------------------------------------------------------------------
// attr (E x 50 f32) -> attrL (E x 64 f16, zero-padded), LINEAR order.
// Pure streaming pass (no scatter); edge kernel reads rows via eid (dense
// random 128B rows, full line utilization).
// ---------------------------------------------------------------------------
__global__ __launch_bounds__(256)
void attr16_kernel(const float* __restrict__ attr, _Float16* __restrict__ attrL, int E)
{
    int idx = blockIdx.x * 256 + threadIdx.x;
    const int stride = gridDim.x * 256;
    const int total = E * 8;
    for (; idx < total; idx += stride) {
        const int e = idx >> 3, sub = idx & 7;
        const float* rp = attr + (size_t)e * 50 + sub * 8;
        v8hf t;
        #pragma unroll
        for (int j = 0; j < 8; ++j) {
            const int c = sub * 8 + j;
            t[j] = (c < 50) ? (_Float16)rp[j] : (_Float16)0.f;
        }
        *(v8hf*)&attrL[(size_t)e * 64 + sub * 8] = t;
    }
}

// ---------------------------------------------------------------------------
// dst-CSR build, trimmed to 3 passes:
//   1) rank_hist: rank[i] = old count (free from the histogram atomicAdd)
//   2) scan (scan1+scan2) -> offs
//   3) build_rec: one 16B record {eid, src, dst, cosC} scattered to its slot
// ---------------------------------------------------------------------------
__global__ __launch_bounds__(256)
void rank_hist_kernel(const int* __restrict__ dst, int* __restrict__ cnt,
                      int* __restrict__ rank, int E)
{
    int i = blockIdx.x * 256 + threadIdx.x;
    const int stride = gridDim.x * 256;
    for (; i < E; i += stride) rank[i] = atomicAdd(&cnt[dst[i]], 1);
}

__global__ __launch_bounds__(256)
void scan1_kernel(int* __restrict__ data, int* __restrict__ bsum, int N)
{
    __shared__ int wsum[4];
    const int t = threadIdx.x, lane = t & 63, wv = t >> 6;
    const int base = blockIdx.x * 1024 + t * 4;
    int v0 = 0, v1 = 0, v2 = 0, v3 = 0;
    if (base + 0 < N) v0 = data[base + 0];
    if (base + 1 < N) v1 = data[base + 1];
    if (base + 2 < N) v2 = data[base + 2];
    if (base + 3 < N) v3 = data[base + 3];
    const int s = v0 + v1 + v2 + v3;
    int sc = s;
    #pragma unroll
    for (int d = 1; d < 64; d <<= 1) {
        int o = __shfl_up(sc, d);
        if (lane >= d) sc += o;
    }
    if (lane == 63) wsum[wv] = sc;
    __syncthreads();
    int wo = 0;
    for (int j = 0; j < wv; ++j) wo += wsum[j];
    int run = wo + (sc - s);
    if (base + 0 < N) data[base + 0] = run; run += v0;
    if (base + 1 < N) data[base + 1] = run; run += v1;
    if (base + 2 < N) data[base + 2] = run; run += v2;
    if (base + 3 < N) data[base + 3] = run; run += v3;
    if (t == 255) bsum[blockIdx.x] = wo + sc;
}

__global__ __launch_bounds__(256)
void scan2_kernel(int* __restrict__ offs, const int* __restrict__ bsum, int N, int E)
{
    int add = 0;
    for (int j = 0; j < (int)blockIdx.x; ++j) add += bsum[j];
    const int base = blockIdx.x * 1024 + threadIdx.x * 4;
    #pragma unroll
    for (int r = 0; r < 4; ++r) {
        int i = base + r;
        if (i < N) offs[i] += add;
    }
    if (blockIdx.x == 0 && threadIdx.x == 0) offs[N] = E;
}

__global__ __launch_bounds__(256)
void build_rec_kernel(const int* __restrict__ src, const int* __restrict__ dst,
                      const float* __restrict__ ew, const int* __restrict__ rank,
                      const int* __restrict__ offs, int4* __restrict__ recP, int E)
{
    int i = blockIdx.x * 256 + threadIdx.x;
    const int stride = gridDim.x * 256;
    for (; i < E; i += stride) {
        const int d = dst[i];
        const int slot = offs[d] + rank[i];
        int4 rec;
        rec.x = i;
        rec.y = src[i];
        rec.z = d;
        rec.w = __float_as_int(0.5f * (__cosf(ew[i] * 0.31415926535897932f) + 1.f));
        recP[slot] = rec;
    }
}

// ---------------------------------------------------------------------------
// Edge kernel v5: DST-SORTED slots + run-merged atomics.
//   - r4 evidence: with reads at 87MB, edge sat at 314us, WRITE 449MB @
//     1.43TB/s -> atomic volume IS the cap. dst-sort makes consecutive slots
//     share dst (avg run 16) -> in-register run-merge over each quad's 4
//     slots cuts atomic ops ~3.4x.
//   - metadata: one coalesced int4 record per slot {eid, src, dst, cC}.
//   - attr: dense f16 rows of attrL via eid (random 128B rows, full lines).
//   - h: random rows but h is 20.5MB -> fully LLC-resident.
//   - barrier-free (Uh wave-private), (256,7).
// ---------------------------------------------------------------------------
__global__ __launch_bounds__(256, 7)
void edge_kernel(const _Float16* __restrict__ attrL, // E x 64, linear
                 const int4* __restrict__ recP,      // E slots, dst-sorted
                 const _Float16* __restrict__ w1f,
                 const _Float16* __restrict__ w2f,
                 const float* __restrict__ b1,
                 const float* __restrict__ b2,
                 const float* __restrict__ h,        // N x 128
                 float* __restrict__ agg,            // N x 128 (zeroed)
                 int E)
{
    __shared__ __align__(16) _Float16 Uh[64 * 138];

    const int tid = threadIdx.x;
    const int e_base = blockIdx.x * 64;
    const int lane = tid & 63, wv = tid >> 6;
    const int m0 = wv * 16, l15 = lane & 15, quad = lane >> 4;

    // ---- per-quad metadata from records (L1-broadcast within quad) ----
    const int s0 = e_base + m0 + quad * 4;
    int dIdx[4]; float cC[4]; const float* hrow[4]; float* arow[4]; bool val[4];
    #pragma unroll
    for (int r = 0; r < 4; ++r) {
        const int sg = s0 + r;
        val[r] = sg < E;
        const int s = val[r] ? sg : (E - 1);
        const int4 rec = recP[s];
        dIdx[r] = rec.z;
        cC[r] = __int_as_float(rec.w);
        hrow[r] = h + (size_t)rec.y * 128;
        arow[r] = agg + (size_t)rec.z * 128;
    }

    // ---- per-lane A-fragment: eid of this lane's slot, dense f16 row ----
    int sA = e_base + m0 + l15;
    if (sA >= E) sA = E - 1;
    const int eidA = ((const int*)recP)[(size_t)sA * 4];
    const _Float16* ap = attrL + (size_t)eidA * 64;
    const v8hf a0 = *(const v8hf*)(ap + quad * 8);
    const v8hf a1 = *(const v8hf*)(ap + 32 + quad * 8);

    // ---- h-gather prefetch (rows LLC-resident; hides behind MFMA) ----
    float hv[8][4];
    #pragma unroll
    for (int nt = 0; nt < 8; ++nt)
        #pragma unroll
        for (int r = 0; r < 4; ++r)
            hv[nt][r] = hrow[r][nt * 16 + l15];

    // ---- stage 1: u = ssp(attr @ W1^T + b1) -> Uh (wave-private rows) ----
    #pragma unroll
    for (int nt = 0; nt < 8; ++nt) {
        v4f acc = {0.f, 0.f, 0.f, 0.f};
        const v8hf bA = *(const v8hf*)&w1f[((nt * 2 + 0) * 64 + lane) * 8];
        const v8hf bB = *(const v8hf*)&w1f[((nt * 2 + 1) * 64 + lane) * 8];
        acc = __builtin_amdgcn_mfma_f32_16x16x32_f16(a0, bA, acc, 0, 0, 0);
        acc = __builtin_amdgcn_mfma_f32_16x16x32_f16(a1, bB, acc, 0, 0, 0);
        const float bj = b1[nt * 16 + l15];
        #pragma unroll
        for (int r = 0; r < 4; ++r)
            Uh[(m0 + quad * 4 + r) * 138 + nt * 16 + l15] =
                (_Float16)ssp_fast(acc[r] + bj);
    }

    // ---- stage 2 + run-merged atomic epilogue ----
    v8hf ua[4];
    #pragma unroll
    for (int ks = 0; ks < 4; ++ks)
        ua[ks] = *(const v8hf*)&Uh[(m0 + l15) * 138 + ks * 32 + quad * 8];

    #pragma unroll
    for (int nt = 0; nt < 8; ++nt) {
        v4f acc = {0.f, 0.f, 0.f, 0.f};
        #pragma unroll
        for (int ks = 0; ks < 4; ++ks) {
            const v8hf b = *(const v8hf*)&w2f[((nt * 4 + ks) * 64 + lane) * 8];
            acc = __builtin_amdgcn_mfma_f32_16x16x32_f16(ua[ks], b, acc, 0, 0, 0);
        }
        const int col = nt * 16 + l15;
        const float bj = b2[col];
        float m[4];
        #pragma unroll
        for (int r = 0; r < 4; ++r)
            m[r] = val[r] ? (acc[r] + bj) * cC[r] * hv[nt][r] : 0.f;
        // run-merge over the quad's 4 consecutive dst-sorted slots
        float run = m[0];
        #pragma unroll
        for (int r = 1; r < 4; ++r) {
            if (dIdx[r] == dIdx[r - 1]) {
                run += m[r];
            } else {
                atomicAdd(arow[r - 1] + col, run);
                run = m[r];
            }
        }
        atomicAdd(arow[3] + col, run);
    }
}

extern "C" void kernel_launch(void* const* d_in, const int* in_sizes, int n_in,
                              void* d_out, int out_size, void* d_ws, size_t ws_size,
                              hipStream_t stream)
{
    const float* x   = (const float*)d_in[0];
    const int*   ei  = (const int*)  d_in[1];
    const float* ew  = (const float*)d_in[2];
    const float* ea  = (const float*)d_in[3];
    const float* w1  = (const float*)d_in[4];
    const float* b1  = (const float*)d_in[5];
    const float* w2  = (const float*)d_in[6];
    const float* b2  = (const float*)d_in[7];
    const float* l1w = (const float*)d_in[8];
    const float* l2w = (const float*)d_in[9];
    const float* l2b = (const float*)d_in[10];
    const float* lw  = (const float*)d_in[11];
    const float* lb  = (const float*)d_in[12];

    const int N = in_sizes[0] / 128;   // 40000
    const int E = in_sizes[2];         // 640000
    const int NB = (N + 1023) / 1024;

    char* base = (char*)d_ws;
    size_t off = 0;
    auto take = [&](size_t bytes) -> char* {
        char* r = base + off;
        off = (off + bytes + 255) & ~(size_t)255;
        return r;
    };
    float*    hbuf  = (float*)   take((size_t)N * 128 * 4);
    float*    agg   = (float*)   take((size_t)N * 128 * 4);
    _Float16* w1f   = (_Float16*)take(8192 * 2);
    _Float16* w2f   = (_Float16*)take(16384 * 2);
    _Float16* l1f   = (_Float16*)take(16384 * 2);
    _Float16* l2f   = (_Float16*)take(16384 * 2);
    _Float16* lwf   = (_Float16*)take(16384 * 2);
    int*      offs  = (int*)     take((size_t)(N + 1) * 4);
    int*      bsum  = (int*)     take((size_t)NB * 4);
    int*      rank  = (int*)     take((size_t)E * 4);
    int4*     recP  = (int4*)    take((size_t)E * 16);
    _Float16* attrL = (_Float16*)take((size_t)E * 64 * 2);

    const int nb = (N + 63) / 64;
    const int eb = (E + 63) / 64;
    const int tb = (E + 255) / 256;

    prep_kernel<<<288, 256, 0, stream>>>(w1, w2, l1w, l2w, lw,
                                         w1f, w2f, l1f, l2f, lwf);
    hipMemsetAsync(agg, 0, (size_t)N * 128 * sizeof(float), stream);
    hipMemsetAsync(offs, 0, (size_t)(N + 1) * sizeof(int), stream);

    attr16_kernel<<<(E * 8 + 255) / 256, 256, 0, stream>>>(ea, attrL, E);
    rank_hist_kernel<<<tb, 256, 0, stream>>>(ei + E, offs, rank, E);
    scan1_kernel<<<NB, 256, 0, stream>>>(offs, bsum, N);
    scan2_kernel<<<NB, 256, 0, stream>>>(offs, bsum, N, E);
    build_rec_kernel<<<tb, 256, 0, stream>>>(ei, ei + E, ew, rank, offs, recP, E);

    h_gemm_kernel<<<dim3(nb, 2), 256, 0, stream>>>(x, l1f, hbuf, N);
    edge_kernel<<<eb, 256, 0, stream>>>(attrL, recP, w1f, w2f, b1, b2,
                                        hbuf, agg, E);
    fused_out_kernel<<<dim3(nb, 2), 256, 0, stream>>>(agg, l2f, l2b, lwf, lb,
                                                      (float*)d_out, N);
}

// Round 6
// 569.727 us; speedup vs baseline: 1.1985x; 1.0096x over previous
//
#include <hip/hip_runtime.h>
#include <math.h>

#define LN2F 0.69314718055994531f

typedef _Float16 v8hf __attribute__((ext_vector_type(8)));
typedef float    v4f  __attribute__((ext_vector_type(4)));

// fast shifted-softplus via v_exp_f32/v_log_f32 (~10 VALU instr vs ~50 libm).
__device__ __forceinline__ float ssp_fast(float x) {
    float e = __expf(-fabsf(x));
    return fmaxf(x, 0.f) + __logf(1.f + e) - LN2F;
}

// ---------------------------------------------------------------------------
// Prep: weights -> f16, MFMA-B-fragment order.
// ---------------------------------------------------------------------------
__global__ __launch_bounds__(256)
void prep_kernel(const float* __restrict__ w1, const float* __restrict__ w2,
                 const float* __restrict__ l1w, const float* __restrict__ l2w,
                 const float* __restrict__ lw,
                 _Float16* __restrict__ w1f, _Float16* __restrict__ w2f,
                 _Float16* __restrict__ l1f, _Float16* __restrict__ l2f,
                 _Float16* __restrict__ lwf)
{
    int idx = blockIdx.x * 256 + threadIdx.x;
    if (idx < 8192) {  // w1f
        int i = idx & 7, lane = (idx >> 3) & 63, ks = (idx >> 9) & 1, nt = idx >> 10;
        int r = nt * 16 + (lane & 15);
        int k = ks * 32 + (lane >> 4) * 8 + i;
        w1f[idx] = (k < 50) ? (_Float16)w1[r * 50 + k] : (_Float16)0.f;
        return;
    }
    int o = idx - 8192;
    if (o >= 4 * 16384) return;
    int which = o >> 14;
    int p = o & 16383;
    int i = p & 7, lane = (p >> 3) & 63, ks = (p >> 9) & 3, nt = p >> 11;
    int r = nt * 16 + (lane & 15);
    int k = ks * 32 + (lane >> 4) * 8 + i;
    const float* src = (which == 0) ? w2 : (which == 1) ? l1w : (which == 2) ? l2w : lw;
    _Float16* dst   = (which == 0) ? w2f : (which == 1) ? l1f : (which == 2) ? l2f : lwf;
    dst[p] = (_Float16)src[r * 128 + k];
}

// ---------------------------------------------------------------------------
// h = X @ W^T (no bias/act). Column-split across blockIdx.y for 2x blocks.
// ---------------------------------------------------------------------------
__global__ __launch_bounds__(256)
void h_gemm_kernel(const float* __restrict__ X, const _Float16* __restrict__ Wf,
                   float* __restrict__ Y, int M)
{
    const int tid = threadIdx.x, lane = tid & 63, wv = tid >> 6;
    const int l15 = lane & 15, quad = lane >> 4;
    const int mb = blockIdx.x * 64 + wv * 16;
    const int nt0 = blockIdx.y * 4;

    const int mA = (mb + l15 < M) ? (mb + l15) : (M - 1);
    v8hf a[4];
    #pragma unroll
    for (int ks = 0; ks < 4; ++ks) {
        const float4* xp = (const float4*)&X[(size_t)mA * 128 + ks * 32 + quad * 8];
        float4 x0 = xp[0], x1 = xp[1];
        v8hf t = {(_Float16)x0.x, (_Float16)x0.y, (_Float16)x0.z, (_Float16)x0.w,
                  (_Float16)x1.x, (_Float16)x1.y, (_Float16)x1.z, (_Float16)x1.w};
        a[ks] = t;
    }
    #pragma unroll
    for (int nt = nt0; nt < nt0 + 4; ++nt) {
        v4f acc = {0.f, 0.f, 0.f, 0.f};
        #pragma unroll
        for (int ks = 0; ks < 4; ++ks) {
            const v8hf b = *(const v8hf*)&Wf[((nt * 4 + ks) * 64 + lane) * 8];
            acc = __builtin_amdgcn_mfma_f32_16x16x32_f16(a[ks], b, acc, 0, 0, 0);
        }
        const int col = nt * 16 + l15;
        #pragma unroll
        for (int r = 0; r < 4; ++r) {
            int row = mb + quad * 4 + r;
            if (row < M) Y[(size_t)row * 128 + col] = acc[r];
        }
    }
}

// ---------------------------------------------------------------------------
// Fused tail: out = ssp(agg @ l2^T + l2b) @ lw^T + lb.
// Stage-2 column-split across blockIdx.y (stage-1 recomputed, MFMA is cheap).
// ---------------------------------------------------------------------------
__global__ __launch_bounds__(256)
void fused_out_kernel(const float* __restrict__ agg, const _Float16* __restrict__ l2f,
                      const float* __restrict__ l2b, const _Float16* __restrict__ lwf,
                      const float* __restrict__ lb, float* __restrict__ out, int M)
{
    __shared__ __align__(16) _Float16 Sh[64 * 138];
    const int tid = threadIdx.x, lane = tid & 63, wv = tid >> 6;
    const int l15 = lane & 15, quad = lane >> 4;
    const int m0 = wv * 16;
    const int gbase = blockIdx.x * 64;
    const int nt0 = blockIdx.y * 4;

    const int mA = (gbase + m0 + l15 < M) ? (gbase + m0 + l15) : (M - 1);
    v8hf a[4];
    #pragma unroll
    for (int ks = 0; ks < 4; ++ks) {
        const float4* xp = (const float4*)&agg[(size_t)mA * 128 + ks * 32 + quad * 8];
        float4 x0 = xp[0], x1 = xp[1];
        v8hf t = {(_Float16)x0.x, (_Float16)x0.y, (_Float16)x0.z, (_Float16)x0.w,
                  (_Float16)x1.x, (_Float16)x1.y, (_Float16)x1.z, (_Float16)x1.w};
        a[ks] = t;
    }
    #pragma unroll
    for (int nt = 0; nt < 8; ++nt) {
        v4f acc = {0.f, 0.f, 0.f, 0.f};
        #pragma unroll
        for (int ks = 0; ks < 4; ++ks) {
            const v8hf b = *(const v8hf*)&l2f[((nt * 4 + ks) * 64 + lane) * 8];
            acc = __builtin_amdgcn_mfma_f32_16x16x32_f16(a[ks], b, acc, 0, 0, 0);
        }
        const float bj = l2b[nt * 16 + l15];
        #pragma unroll
        for (int r = 0; r < 4; ++r)
            Sh[(m0 + quad * 4 + r) * 138 + nt * 16 + l15] =
                (_Float16)ssp_fast(acc[r] + bj);
    }
    v8hf ua[4];
    #pragma unroll
    for (int ks = 0; ks < 4; ++ks)
        ua[ks] = *(const v8hf*)&Sh[(m0 + l15) * 138 + ks * 32 + quad * 8];

    #pragma unroll
    for (int nt = nt0; nt < nt0 + 4; ++nt) {
        v4f acc = {0.f, 0.f, 0.f, 0.f};
        #pragma unroll
        for (int ks = 0; ks < 4; ++ks) {
            const v8hf b = *(const v8hf*)&lwf[((nt * 4 + ks) * 64 + lane) * 8];
            acc = __builtin_amdgcn_mfma_f32_16x16x32_f16(ua[ks], b, acc, 0, 0, 0);
        }
        const int col = nt * 16 + l15;
        const float bj = lb[col];
        #pragma unroll
        for (int r = 0; r < 4; ++r) {
            int row = gbase + m0 + quad * 4 + r;
            if (row < M) out[(size_t)row * 128 + col] = acc[r] + bj;
        }
    }
}

// ---------------------------------------------------------------------------
// attr (E x 50 f32) -> attrL (E x 64 f16, zero-padded), LINEAR order.
// ---------------------------------------------------------------------------
__global__ __launch_bounds__(256)
void attr16_kernel(const float* __restrict__ attr, _Float16* __restrict__ attrL, int E)
{
    int idx = blockIdx.x * 256 + threadIdx.x;
    const int stride = gridDim.x * 256;
    const int total = E * 8;
    for (; idx < total; idx += stride) {
        const int e = idx >> 3, sub = idx & 7;
        const float* rp = attr + (size_t)e * 50 + sub * 8;
        v8hf t;
        #pragma unroll
        for (int j = 0; j < 8; ++j) {
            const int c = sub * 8 + j;
            t[j] = (c < 50) ? (_Float16)rp[j] : (_Float16)0.f;
        }
        *(v8hf*)&attrL[(size_t)e * 64 + sub * 8] = t;
    }
}

// ---------------------------------------------------------------------------
// dst-CSR build: rank from histogram atomic return; scan; 16B record scatter.
// ---------------------------------------------------------------------------
__global__ __launch_bounds__(256)
void rank_hist_kernel(const int* __restrict__ dst, int* __restrict__ cnt,
                      int* __restrict__ rank, int E)
{
    int i = blockIdx.x * 256 + threadIdx.x;
    const int stride = gridDim.x * 256;
    for (; i < E; i += stride) rank[i] = atomicAdd(&cnt[dst[i]], 1);
}

__global__ __launch_bounds__(256)
void scan1_kernel(int* __restrict__ data, int* __restrict__ bsum, int N)
{
    __shared__ int wsum[4];
    const int t = threadIdx.x, lane = t & 63, wv = t >> 6;
    const int base = blockIdx.x * 1024 + t * 4;
    int v0 = 0, v1 = 0, v2 = 0, v3 = 0;
    if (base + 0 < N) v0 = data[base + 0];
    if (base + 1 < N) v1 = data[base + 1];
    if (base + 2 < N) v2 = data[base + 2];
    if (base + 3 < N) v3 = data[base + 3];
    const int s = v0 + v1 + v2 + v3;
    int sc = s;
    #pragma unroll
    for (int d = 1; d < 64; d <<= 1) {
        int o = __shfl_up(sc, d);
        if (lane >= d) sc += o;
    }
    if (lane == 63) wsum[wv] = sc;
    __syncthreads();
    int wo = 0;
    for (int j = 0; j < wv; ++j) wo += wsum[j];
    int run = wo + (sc - s);
    if (base + 0 < N) data[base + 0] = run; run += v0;
    if (base + 1 < N) data[base + 1] = run; run += v1;
    if (base + 2 < N) data[base + 2] = run; run += v2;
    if (base + 3 < N) data[base + 3] = run; run += v3;
    if (t == 255) bsum[blockIdx.x] = wo + sc;
}

__global__ __launch_bounds__(256)
void scan2_kernel(int* __restrict__ offs, const int* __restrict__ bsum, int N, int E)
{
    int add = 0;
    for (int j = 0; j < (int)blockIdx.x; ++j) add += bsum[j];
    const int base = blockIdx.x * 1024 + threadIdx.x * 4;
    #pragma unroll
    for (int r = 0; r < 4; ++r) {
        int i = base + r;
        if (i < N) offs[i] += add;
    }
    if (blockIdx.x == 0 && threadIdx.x == 0) offs[N] = E;
}

__global__ __launch_bounds__(256)
void build_rec_kernel(const int* __restrict__ src, const int* __restrict__ dst,
                      const float* __restrict__ ew, const int* __restrict__ rank,
                      const int* __restrict__ offs, int4* __restrict__ recP, int E)
{
    int i = blockIdx.x * 256 + threadIdx.x;
    const int stride = gridDim.x * 256;
    for (; i < E; i += stride) {
        const int d = dst[i];
        const int slot = offs[d] + rank[i];
        int4 rec;
        rec.x = i;
        rec.y = src[i];
        rec.z = d;
        rec.w = __float_as_int(0.5f * (__cosf(ew[i] * 0.31415926535897932f) + 1.f));
        recP[slot] = rec;
    }
}

// ---------------------------------------------------------------------------
// Edge kernel v6: PERSISTENT blocks + RESIDENT weights.
//   r0-r5 invariant diagnosed: every wave re-read 48KB of w1f/w2f B-frags
//   from L2 (>L1) -> 40K waves x 48KB = ~2GB L2 traffic = the ~250-345us
//   floor (invisible in FETCH_SIZE: those were L2 hits).
//   Fix: 512 persistent blocks (2/CU); per block stage w1f->LDS once and
//   w2f->128 VGPRs/lane once (MFMA B-operands straight from registers),
//   biases->regs; then grid-stride over ~20 edge tiles with ZERO weight
//   traffic in the loop. Weight staging total: 24MB (was 2GB).
//   dst-sorted slots + run-merged atomics kept from r5 (WRITE 220MB).
//   LDS = 16K (W1s) + 17.25K (Uh) = 33.3KB; launch_bounds(256,2) caps
//   VGPR at 256 (est ~240 used).
// ---------------------------------------------------------------------------
__global__ __launch_bounds__(256, 2)
void edge_kernel(const _Float16* __restrict__ attrL, // E x 64, linear
                 const int4* __restrict__ recP,      // E slots, dst-sorted
                 const _Float16* __restrict__ w1f,
                 const _Float16* __restrict__ w2f,
                 const float* __restrict__ b1,
                 const float* __restrict__ b2,
                 const float* __restrict__ h,        // N x 128
                 float* __restrict__ agg,            // N x 128 (zeroed)
                 int E, int nTiles)
{
    __shared__ __align__(16) _Float16 W1s[8192];     // 16KB
    __shared__ __align__(16) _Float16 Uh[64 * 138];  // 17.25KB

    const int tid = threadIdx.x;
    const int lane = tid & 63, wv = tid >> 6;
    const int m0 = wv * 16, l15 = lane & 15, quad = lane >> 4;

    // ---- one-time staging: w1 -> LDS ----
    #pragma unroll
    for (int i = 0; i < 4; ++i)
        ((v8hf*)W1s)[tid + 256 * i] = ((const v8hf*)w1f)[tid + 256 * i];

    // ---- one-time: w2 B-fragments -> 128 VGPRs per lane ----
    v8hf w2r[32];
    #pragma unroll
    for (int f = 0; f < 32; ++f)
        w2r[f] = *(const v8hf*)&w2f[((size_t)f * 64 + lane) * 8];

    // ---- one-time: biases (col = nt*16+l15) ----
    float b1v[8], b2v[8];
    #pragma unroll
    for (int nt = 0; nt < 8; ++nt) {
        b1v[nt] = b1[nt * 16 + l15];
        b2v[nt] = b2[nt * 16 + l15];
    }
    __syncthreads();

    for (int tile = blockIdx.x; tile < nTiles; tile += (int)gridDim.x) {
        const int e_base = tile * 64;

        // ---- per-quad metadata from records ----
        const int s0 = e_base + m0 + quad * 4;
        int dIdx[4]; float cC[4]; const float* hrow[4]; float* arow[4]; bool val[4];
        #pragma unroll
        for (int r = 0; r < 4; ++r) {
            const int sg = s0 + r;
            val[r] = sg < E;
            const int s = val[r] ? sg : (E - 1);
            const int4 rec = recP[s];
            dIdx[r] = rec.z;
            cC[r] = __int_as_float(rec.w);
            hrow[r] = h + (size_t)rec.y * 128;
            arow[r] = agg + (size_t)rec.z * 128;
        }

        // ---- per-lane A-fragment: dense f16 row via eid ----
        int sA = e_base + m0 + l15;
        if (sA >= E) sA = E - 1;
        const int eidA = ((const int*)recP)[(size_t)sA * 4];
        const _Float16* ap = attrL + (size_t)eidA * 64;
        const v8hf a0 = *(const v8hf*)(ap + quad * 8);
        const v8hf a1 = *(const v8hf*)(ap + 32 + quad * 8);

        // ---- h-gather prefetch (consumed in epilogue) ----
        float hv[8][4];
        #pragma unroll
        for (int nt = 0; nt < 8; ++nt)
            #pragma unroll
            for (int r = 0; r < 4; ++r)
                hv[nt][r] = hrow[r][nt * 16 + l15];

        // ---- stage 1: u = ssp(attr @ W1^T + b1) -> Uh (wave-private) ----
        #pragma unroll
        for (int nt = 0; nt < 8; ++nt) {
            v4f acc = {0.f, 0.f, 0.f, 0.f};
            const v8hf bA = *(const v8hf*)&W1s[((nt * 2 + 0) * 64 + lane) * 8];
            const v8hf bB = *(const v8hf*)&W1s[((nt * 2 + 1) * 64 + lane) * 8];
            acc = __builtin_amdgcn_mfma_f32_16x16x32_f16(a0, bA, acc, 0, 0, 0);
            acc = __builtin_amdgcn_mfma_f32_16x16x32_f16(a1, bB, acc, 0, 0, 0);
            const float bj = b1v[nt];
            #pragma unroll
            for (int r = 0; r < 4; ++r)
                Uh[(m0 + quad * 4 + r) * 138 + nt * 16 + l15] =
                    (_Float16)ssp_fast(acc[r] + bj);
        }

        // ---- stage 2 (w2 from VGPRs) + run-merged atomic epilogue ----
        v8hf ua[4];
        #pragma unroll
        for (int ks = 0; ks < 4; ++ks)
            ua[ks] = *(const v8hf*)&Uh[(m0 + l15) * 138 + ks * 32 + quad * 8];

        #pragma unroll
        for (int nt = 0; nt < 8; ++nt) {
            v4f acc = {0.f, 0.f, 0.f, 0.f};
            #pragma unroll
            for (int ks = 0; ks < 4; ++ks)
                acc = __builtin_amdgcn_mfma_f32_16x16x32_f16(ua[ks], w2r[nt * 4 + ks],
                                                             acc, 0, 0, 0);
            const int col = nt * 16 + l15;
            const float bj = b2v[nt];
            float m[4];
            #pragma unroll
            for (int r = 0; r < 4; ++r)
                m[r] = val[r] ? (acc[r] + bj) * cC[r] * hv[nt][r] : 0.f;
            float run = m[0];
            #pragma unroll
            for (int r = 1; r < 4; ++r) {
                if (dIdx[r] == dIdx[r - 1]) {
                    run += m[r];
                } else {
                    atomicAdd(arow[r - 1] + col, run);
                    run = m[r];
                }
            }
            atomicAdd(arow[3] + col, run);
        }
    }
}

extern "C" void kernel_launch(void* const* d_in, const int* in_sizes, int n_in,
                              void* d_out, int out_size, void* d_ws, size_t ws_size,
                              hipStream_t stream)
{
    const float* x   = (const float*)d_in[0];
    const int*   ei  = (const int*)  d_in[1];
    const float* ew  = (const float*)d_in[2];
    const float* ea  = (const float*)d_in[3];
    const float* w1  = (const float*)d_in[4];
    const float* b1  = (const float*)d_in[5];
    const float* w2  = (const float*)d_in[6];
    const float* b2  = (const float*)d_in[7];
    const float* l1w = (const float*)d_in[8];
    const float* l2w = (const float*)d_in[9];
    const float* l2b = (const float*)d_in[10];
    const float* lw  = (const float*)d_in[11];
    const float* lb  = (const float*)d_in[12];

    const int N = in_sizes[0] / 128;   // 40000
    const int E = in_sizes[2];         // 640000
    const int NB = (N + 1023) / 1024;

    char* base = (char*)d_ws;
    size_t off = 0;
    auto take = [&](size_t bytes) -> char* {
        char* r = base + off;
        off = (off + bytes + 255) & ~(size_t)255;
        return r;
    };
    float*    hbuf  = (float*)   take((size_t)N * 128 * 4);
    float*    agg   = (float*)   take((size_t)N * 128 * 4);
    _Float16* w1f   = (_Float16*)take(8192 * 2);
    _Float16* w2f   = (_Float16*)take(16384 * 2);
    _Float16* l1f   = (_Float16*)take(16384 * 2);
    _Float16* l2f   = (_Float16*)take(16384 * 2);
    _Float16* lwf   = (_Float16*)take(16384 * 2);
    int*      offs  = (int*)     take((size_t)(N + 1) * 4);
    int*      bsum  = (int*)     take((size_t)NB * 4);
    int*      rank  = (int*)     take((size_t)E * 4);
    int4*     recP  = (int4*)    take((size_t)E * 16);
    _Float16* attrL = (_Float16*)take((size_t)E * 64 * 2);

    const int nb = (N + 63) / 64;
    const int tb = (E + 255) / 256;
    const int nTiles = (E + 63) / 64;

    prep_kernel<<<288, 256, 0, stream>>>(w1, w2, l1w, l2w, lw,
                                         w1f, w2f, l1f, l2f, lwf);
    hipMemsetAsync(agg, 0, (size_t)N * 128 * sizeof(float), stream);
    hipMemsetAsync(offs, 0, (size_t)(N + 1) * sizeof(int), stream);

    attr16_kernel<<<(E * 8 + 255) / 256, 256, 0, stream>>>(ea, attrL, E);
    rank_hist_kernel<<<tb, 256, 0, stream>>>(ei + E, offs, rank, E);
    scan1_kernel<<<NB, 256, 0, stream>>>(offs, bsum, N);
    scan2_kernel<<<NB, 256, 0, stream>>>(offs, bsum, N, E);
    build_rec_kernel<<<tb, 256, 0, stream>>>(ei, ei + E, ew, rank, offs, recP, E);

    h_gemm_kernel<<<dim3(nb, 2), 256, 0, stream>>>(x, l1f, hbuf, N);
    edge_kernel<<<512, 256, 0, stream>>>(attrL, recP, w1f, w2f, b1, b2,
                                         hbuf, agg, E, nTiles);
    fused_out_kernel<<<dim3(nb, 2), 256, 0, stream>>>(agg, l2f, l2b, lwf, lb,
                                                      (float*)d_out, N);
}